// Round 10
// baseline (149.601 us; speedup 1.0000x reference)
//
#include <hip/hip_runtime.h>
#include <math.h>

#define TD 128     // feature dimension
#define BT 64      // fallback tile rows
#define TILE 256   // tile rows per 4-wave block
#define GRIDB 1024 // grid blocks (4/CU nominal)
#define NXCD 8

typedef _Float16 half8 __attribute__((ext_vector_type(8)));
typedef _Float16 half2v __attribute__((ext_vector_type(2)));
typedef float f32x4 __attribute__((ext_vector_type(4)));

// K = exp(-d2/(2*10^2)) = 2^(C2*d2);  C2 = -1/(200*ln2).
// Inputs are pre-scaled by SCL = sqrt(1/(100 ln2)) so the MFMA dot IS the
// exp2 exponent contribution: exponent = -.5|zs_i|^2 -.5|zs_j|^2 + zs_i.zs_j.
#define SCLf 0.12011224f

#if __has_builtin(__builtin_amdgcn_exp2f)
#define EXP2F(x) __builtin_amdgcn_exp2f(x)
#else
#define EXP2F(x) exp2f(x)
#endif

__device__ __forceinline__ void decode_tile(int t, int T, int& bi, int& bj) {
    double bguess = (2.0 * T + 1.0 -
                     sqrt((2.0 * T + 1.0) * (2.0 * T + 1.0) - 8.0 * (double)t)) * 0.5;
    int b = (int)bguess;
    if (b < 0) b = 0;
    if (b > T - 1) b = T - 1;
    while ((b + 1) * T - ((b + 1) * b) / 2 <= t) ++b;
    while (b * T - (b * (b - 1)) / 2 > t) --b;
    bi = b;
    bj = b + (t - (b * T - (b * (b - 1)) / 2));
}

// ---------------------------------------------------------------------------
// Prologue: Z -> SCALED fp16 + En[r] = exp2(-0.5*||zs_r||^2)  (from the
// rounded scaled values -> exponent consistent with MFMA dots; diag = 1)
// ---------------------------------------------------------------------------
__global__ __launch_bounds__(256) void cvt_norms_kernel(const float* __restrict__ X,
                                                        const float* __restrict__ Y,
                                                        int n, int tot,
                                                        _Float16* __restrict__ Z16,
                                                        float* __restrict__ En) {
    const int wid  = (blockIdx.x * 256 + threadIdx.x) >> 6;
    const int lane = threadIdx.x & 63;
    if (wid >= tot) return;
    const float* row = (wid < n) ? (X + (size_t)wid * TD) : (Y + (size_t)(wid - n) * TD);
    float2 v = *reinterpret_cast<const float2*>(row + lane * 2);
    _Float16 hx = (_Float16)(v.x * SCLf);
    _Float16 hy = (_Float16)(v.y * SCLf);
    half2v h2 = {hx, hy};
    *reinterpret_cast<half2v*>(Z16 + (size_t)wid * TD + lane * 2) = h2;
    float fx = (float)hx, fy = (float)hy;
    float s = fmaf(fx, fx, fy * fy);
#pragma unroll
    for (int off = 32; off > 0; off >>= 1) s += __shfl_down(s, off, 64);
    if (lane == 0) En[wid] = EXP2F(-0.5f * s);
}

// ---------------------------------------------------------------------------
// Main: NO LDS, NO barriers.  Panels are L2-resident (4MB Z16 total,
// XCD-partitioned tile ranges); MFMA fragments are read DIRECTLY from
// global (16 rows x 64B coalesced segments per wave-load, L1/L2-served).
// r4-r9 lesson: the barrier-phased LDS pipeline was latency-bound at every
// phase edge with all pipes <=35% busy -- so remove the phases entirely and
// let waves free-run.  256 thr / 4 waves (proven no-spill codegen shape);
// block tile 256x256, wave = 64 cols x (two 128-row passes, acc[8][4]).
// Per-pair epilogue: 1 exp2 + 1 fma (scale pre-folded into fp16 inputs).
// ---------------------------------------------------------------------------
__global__ __launch_bounds__(256, 2)
void mmd_direct_kernel(const _Float16* __restrict__ Z16,
                       const float* __restrict__ En,
                       double* __restrict__ partials,
                       int n, int m, int T, int ntiles) {
    const int tid = threadIdx.x;
    const int l = tid & 63;
    const int w = tid >> 6;            // wave 0..3
    const int lr = l & 15;             // A-row / B-col within 16-block
    const int kq = l >> 4;             // k-quarter (16B slot within 64B)
    const int wcol = w * 64;

    const f32x4 zero4 = {0.f, 0.f, 0.f, 0.f};
    double acc_d = 0.0;

    // XCD-partitioned persistent tile range
    const int per_xcd = (ntiles + NXCD - 1) / NXCD;
    const int xcd = blockIdx.x & (NXCD - 1);
    const int bidx = blockIdx.x >> 3;
    const int stride = GRIDB / NXCD;   // 128
    int tend = xcd * per_xcd + per_xcd;
    if (tend > ntiles) tend = ntiles;

    for (int it = xcd * per_xcd + bidx; it < tend; it += stride) {
        int bi, bj;
        decode_tile(it, T, bi, bj);
        const char* gA = (const char*)Z16 + (size_t)bi * (TILE * TD * 2);
        const char* gB = (const char*)Z16 + (size_t)bj * (TILE * TD * 2)
                                          + (size_t)wcol * (TD * 2);
        const float* EnA = En + (size_t)bi * TILE;
        const float* EnB = En + (size_t)bj * TILE + wcol;

        float s2 = 0.f;
#pragma unroll
        for (int half = 0; half < 2; ++half) {
            const char* gAh = gA + half * 128 * (TD * 2);
            f32x4 acc[8][4];

            // ---- K=128 in 4 quarters of 32; fragments straight from global
#pragma unroll
            for (int ks = 0; ks < 4; ++ks) {
                const int koff = ks * 64 + kq * 16;
                half8 bf[4];
#pragma unroll
                for (int j = 0; j < 4; ++j)
                    bf[j] = *reinterpret_cast<const half8*>(gB + (j * 16 + lr) * 256 + koff);
#pragma unroll
                for (int i = 0; i < 8; ++i) {
                    half8 af = *reinterpret_cast<const half8*>(gAh + (i * 16 + lr) * 256 + koff);
#pragma unroll
                    for (int j = 0; j < 4; ++j)
                        acc[i][j] = __builtin_amdgcn_mfma_f32_16x16x32_f16(
                            af, bf[j], (ks == 0) ? zero4 : acc[i][j], 0, 0, 0);
                }
            }

            // ---- epilogue: K = Ei * Ej * exp2(acc); En lazily from global
            float s = 0.f;
#pragma unroll
            for (int j = 0; j < 4; ++j) {
                float Ejv = EnB[j * 16 + lr];
                float sj0 = 0.f, sj1 = 0.f;
#pragma unroll
                for (int i = 0; i < 8; ++i) {
                    f32x4 Eiv = *reinterpret_cast<const f32x4*>(EnA + half * 128 + i * 16 + kq * 4);
#pragma unroll
                    for (int r = 0; r < 4; ++r) {
                        float e = EXP2F(acc[i][j][r]);
                        if (r & 1) sj1 = fmaf(Eiv[r], e, sj1);
                        else       sj0 = fmaf(Eiv[r], e, sj0);
                    }
                }
                s = fmaf(Ejv, sj0 + sj1, s);
            }
            s2 += s;
        }

        // ---- wave reduce -> running double accumulator
#pragma unroll
        for (int off = 32; off > 0; off >>= 1) s2 += __shfl_down(s2, off, 64);
        {
            double wa = (bi * TILE < n) ? (1.0 / (double)n) : (-1.0 / (double)m);
            double wb = (bj * TILE < n) ? (1.0 / (double)n) : (-1.0 / (double)m);
            double wgt = wa * wb * ((bi == bj) ? 1.0 : 2.0);
            acc_d += wgt * (double)s2;   // lane 0 holds the wave sum
        }
    }

    if (l == 0) partials[(size_t)blockIdx.x * 4 + w] = acc_d;
}

// ---------------------------------------------------------------------------
// Fallback fp32 path (round-1, proven): used only if ws/shape unsuitable
// ---------------------------------------------------------------------------
__global__ __launch_bounds__(256) void norms_kernel(const float* __restrict__ X,
                                                    const float* __restrict__ Y,
                                                    int n, int tot,
                                                    float* __restrict__ norms) {
    int r = blockIdx.x * 256 + threadIdx.x;
    if (r >= tot) return;
    const float* row = (r < n) ? (X + (size_t)r * TD) : (Y + (size_t)(r - n) * TD);
    float s = 0.f;
#pragma unroll
    for (int k = 0; k < TD; k += 4) {
        float4 v = *reinterpret_cast<const float4*>(row + k);
        s = fmaf(v.x, v.x, s); s = fmaf(v.y, v.y, s);
        s = fmaf(v.z, v.z, s); s = fmaf(v.w, v.w, s);
    }
    norms[r] = s;
}

__global__ __launch_bounds__(256, 2) void mmd_tile_kernel(const float* __restrict__ X,
                                                          const float* __restrict__ Y,
                                                          const float* __restrict__ norms,
                                                          double* __restrict__ partials,
                                                          int n, int m, int T) {
    __shared__ float sA[TD][BT];
    __shared__ float sB[TD][BT];
    __shared__ float sredf[4];

    const int t = blockIdx.x;
    int bi, bj;
    decode_tile(t, T, bi, bj);

    const int tid = threadIdx.x;
    {
        const int row = tid & 63;
        const int qb  = tid >> 6;
        const int ra = bi * BT + row;
        const int rb = bj * BT + row;
        const float* Arow = (ra < n) ? (X + (size_t)ra * TD) : (Y + (size_t)(ra - n) * TD);
        const float* Brow = (rb < n) ? (X + (size_t)rb * TD) : (Y + (size_t)(rb - n) * TD);
#pragma unroll
        for (int i = 0; i < 8; ++i) {
            const int q = qb + 4 * i;
            float4 va = *reinterpret_cast<const float4*>(Arow + 4 * q);
            sA[4 * q + 0][row] = va.x; sA[4 * q + 1][row] = va.y;
            sA[4 * q + 2][row] = va.z; sA[4 * q + 3][row] = va.w;
            float4 vb = *reinterpret_cast<const float4*>(Brow + 4 * q);
            sB[4 * q + 0][row] = vb.x; sB[4 * q + 1][row] = vb.y;
            sB[4 * q + 2][row] = vb.z; sB[4 * q + 3][row] = vb.w;
        }
    }
    __syncthreads();

    const int tx = tid & 15;
    const int ty = tid >> 4;
    float acc[4][4];
#pragma unroll
    for (int i = 0; i < 4; ++i)
#pragma unroll
        for (int j = 0; j < 4; ++j) acc[i][j] = 0.f;

#pragma unroll 16
    for (int k = 0; k < TD; ++k) {
        float4 a = *reinterpret_cast<const float4*>(&sA[k][ty * 4]);
        float4 b = *reinterpret_cast<const float4*>(&sB[k][tx * 4]);
        const float av[4] = {a.x, a.y, a.z, a.w};
        const float bv[4] = {b.x, b.y, b.z, b.w};
#pragma unroll
        for (int i = 0; i < 4; ++i)
#pragma unroll
            for (int j = 0; j < 4; ++j)
                acc[i][j] = fmaf(av[i], bv[j], acc[i][j]);
    }

    float nA[4], nB[4];
#pragma unroll
    for (int i = 0; i < 4; ++i) nA[i] = norms[bi * BT + ty * 4 + i];
#pragma unroll
    for (int j = 0; j < 4; ++j) nB[j] = norms[bj * BT + tx * 4 + j];

    const float cexp = -0.005f;
    float s = 0.f;
#pragma unroll
    for (int i = 0; i < 4; ++i)
#pragma unroll
        for (int j = 0; j < 4; ++j) {
            float d2 = fmaxf(nA[i] + nB[j] - 2.f * acc[i][j], 0.f);
            s += __expf(d2 * cexp);
        }

#pragma unroll
    for (int off = 32; off > 0; off >>= 1) s += __shfl_down(s, off, 64);
    if ((tid & 63) == 0) sredf[tid >> 6] = s;
    __syncthreads();
    if (tid == 0) {
        double wa = (bi * BT < n) ? (1.0 / (double)n) : (-1.0 / (double)m);
        double wb = (bj * BT < n) ? (1.0 / (double)n) : (-1.0 / (double)m);
        double wgt = wa * wb * ((bi == bj) ? 1.0 : 2.0);
        partials[t] = wgt * (double)(sredf[0] + sredf[1] + sredf[2] + sredf[3]);
    }
}

// ---------------------------------------------------------------------------
__global__ __launch_bounds__(256) void reduce_kernel(const double* __restrict__ partials,
                                                     int npart,
                                                     float* __restrict__ out) {
    __shared__ double sd[256];
    double s = 0.0;
    for (int i = threadIdx.x; i < npart; i += 256) s += partials[i];
    sd[threadIdx.x] = s;
    __syncthreads();
    for (int off = 128; off > 0; off >>= 1) {
        if ((int)threadIdx.x < off) sd[threadIdx.x] += sd[threadIdx.x + off];
        __syncthreads();
    }
    if (threadIdx.x == 0) out[0] = (float)sd[0];
}

// ---------------------------------------------------------------------------
extern "C" void kernel_launch(void* const* d_in, const int* in_sizes, int n_in,
                              void* d_out, int out_size, void* d_ws, size_t ws_size,
                              hipStream_t stream) {
    const float* X = (const float*)d_in[0];
    const float* Y = (const float*)d_in[1];
    float* out = (float*)d_out;

    const int n = in_sizes[0] / TD;
    const int m = in_sizes[1] / TD;
    const int tot = n + m;

    // fp16-MFMA path workspace: Z16 + En + per-(block,wave) partials
    const size_t z16_bytes = (size_t)tot * TD * 2;
    const size_t en_off    = (z16_bytes + 255) & ~(size_t)255;
    const size_t en_bytes  = (size_t)tot * 4;
    const size_t part_off  = ((en_off + en_bytes) + 255) & ~(size_t)255;
    const int Tm = tot / TILE;
    const int npart_m = Tm * (Tm + 1) / 2;
    const int nred = GRIDB * 4;
    const size_t needed = part_off + (size_t)nred * 8;

    if (ws_size >= needed && (tot % TILE) == 0 && (n % TILE) == 0) {
        _Float16* Z16 = (_Float16*)d_ws;
        float* En = (float*)((char*)d_ws + en_off);
        double* partials = (double*)((char*)d_ws + part_off);
        cvt_norms_kernel<<<(tot + 3) / 4, 256, 0, stream>>>(X, Y, n, tot, Z16, En);
        mmd_direct_kernel<<<GRIDB, 256, 0, stream>>>(Z16, En, partials, n, m, Tm, npart_m);
        reduce_kernel<<<1, 256, 0, stream>>>(partials, nred, out);
    } else {
        const int T = tot / BT;
        const int npart = T * (T + 1) / 2;
        float* norms = (float*)d_ws;
        double* partials = (double*)((char*)d_ws + (((size_t)tot * 4 + 255) & ~(size_t)255));
        norms_kernel<<<(tot + 255) / 256, 256, 0, stream>>>(X, Y, n, tot, norms);
        mmd_tile_kernel<<<npart, 256, 0, stream>>>(X, Y, norms, partials, n, m, T);
        reduce_kernel<<<1, 256, 0, stream>>>(partials, npart, out);
    }
}

// Round 11
// 67.459 us; speedup vs baseline: 2.2177x; 2.2177x over previous
//
#include <hip/hip_runtime.h>
#include <math.h>

#define TD 128     // feature dimension
#define BT 64      // fallback tile rows
#define TILE 128   // mfma tile rows per block tile
#define GRIDB 1024 // persistent blocks, 4 per CU
#define NXCD 8

typedef _Float16 half8 __attribute__((ext_vector_type(8)));
typedef _Float16 half2v __attribute__((ext_vector_type(2)));
typedef float f32x4 __attribute__((ext_vector_type(4)));

// K = exp(-d2/(2*10^2)) = 2^(C2*d2);  C2 = -1/(200*ln2).
// Inputs pre-scaled by SCL = sqrt(1/(100 ln2)) so the MFMA dot IS the exp2
// exponent: karg = -.5|zs_i|^2 -.5|zs_j|^2 + zs_i.zs_j, K = Ei*Ej*2^dot.
#define SCLf 0.12011224f

#if __has_builtin(__builtin_amdgcn_exp2f)
#define EXP2F(x) __builtin_amdgcn_exp2f(x)
#else
#define EXP2F(x) exp2f(x)
#endif

// LDS layout (bytes): 4 quarter-K panels [128 rows][32 fp16 = 64B] = 8KB each
// A0@0, A1@8K, B0@16K, B1@24K, EnA@32K (512B), EnB@32K+512 (512B)
#define LA0 0
#define LA1 8192
#define LB0 16384
#define LB1 24576
#define LEA 32768
#define LEB 33280
#define LDS_TOT 33792

#define SCHEDB() __builtin_amdgcn_sched_barrier(0)

__device__ __forceinline__ void gload16(const void* g, void* l) {
    __builtin_amdgcn_global_load_lds(
        (const __attribute__((address_space(1))) void*)g,
        (__attribute__((address_space(3))) void*)l, 16, 0, 0);
}

__device__ __forceinline__ void decode_tile(int t, int T, int& bi, int& bj) {
    double bguess = (2.0 * T + 1.0 -
                     sqrt((2.0 * T + 1.0) * (2.0 * T + 1.0) - 8.0 * (double)t)) * 0.5;
    int b = (int)bguess;
    if (b < 0) b = 0;
    if (b > T - 1) b = T - 1;
    while ((b + 1) * T - ((b + 1) * b) / 2 <= t) ++b;
    while (b * T - (b * (b - 1)) / 2 > t) --b;
    bi = b;
    bj = b + (t - (b * T - (b * (b - 1)) / 2));
}

// ---------------------------------------------------------------------------
// Prologue: Z -> SCALED fp16 + En[r] = exp2(-0.5*||zs_r||^2) (from rounded
// scaled values -> exponents consistent with the MFMA dots; diagonal = 1)
// ---------------------------------------------------------------------------
__global__ __launch_bounds__(256) void cvt_norms_kernel(const float* __restrict__ X,
                                                        const float* __restrict__ Y,
                                                        int n, int tot,
                                                        _Float16* __restrict__ Z16,
                                                        float* __restrict__ En) {
    const int wid  = (blockIdx.x * 256 + threadIdx.x) >> 6;
    const int lane = threadIdx.x & 63;
    if (wid >= tot) return;
    const float* row = (wid < n) ? (X + (size_t)wid * TD) : (Y + (size_t)(wid - n) * TD);
    float2 v = *reinterpret_cast<const float2*>(row + lane * 2);
    _Float16 hx = (_Float16)(v.x * SCLf);
    _Float16 hy = (_Float16)(v.y * SCLf);
    half2v h2 = {hx, hy};
    *reinterpret_cast<half2v*>(Z16 + (size_t)wid * TD + lane * 2) = h2;
    float fx = (float)hx, fy = (float)hy;
    float s = fmaf(fx, fx, fy * fy);
#pragma unroll
    for (int off = 32; off > 0; off >>= 1) s += __shfl_down(s, off, 64);
    if (lane == 0) En[wid] = EXP2F(-0.5f * s);
}

// ---------------------------------------------------------------------------
// Main: 128x128 triangular tiles, 256 thr / 4 waves, 33KB LDS ->
// 4 independent blocks/CU (cross-block fill of each other's phase gaps;
// quartered tile granularity cuts the ceil() tail 23%->12%).
// launch_bounds(256,2): the only compile shapes that ever spilled were
// second-arg-4 / 1024-thr (r6-r8); (256,2) gave 88-128 VGPR clean.
// Wave = 64x64 (acc[4][4]); K=128 in four 32-quarters, ping-pong buffers,
// counted vmcnt (never 0 until last tile), stage-under-compute, XCD-
// partitioned ranges, per-wave double accumulator, swizzle pair from r8
// (measured 0 bank conflicts at this geometry).
// ---------------------------------------------------------------------------
__global__ __launch_bounds__(256, 2)
void mmd_pipe_kernel(const _Float16* __restrict__ Z16,
                     const float* __restrict__ En,
                     double* __restrict__ partials,
                     int n, int m, int T, int ntiles) {
    __shared__ char lds[LDS_TOT];

    const int tid = threadIdx.x;
    const int l = tid & 63;
    const int w = tid >> 6;            // wave 0..3
    const int lr = l & 15;             // row/col within 16-block
    const int kq = l >> 4;             // 16B k-slot within 64B row
    const int soff = (kq ^ ((lr >> 1) & 3)) << 4;   // swizzled frag byte off
    const int wrow = (w >> 1) * 64;    // 0 or 64
    const int wcol = (w & 1) * 64;     // 0 or 64

    // staging: quarter = 128 rows x 64B = 8 chunks of 1KB (16 rows);
    // wave w owns chunks {2w, 2w+1}; lane l -> row l>>2, slot l&3,
    // source slot inverse-swizzled by (row>>1)&3 = (l>>3)&3 (r8-verified).
    const int g16 = ((l & 3) ^ ((l >> 3) & 3)) << 4;
    const int r0 = w * 32 + (l >> 2);
    const int r1 = r0 + 16;
    const int lc0 = (w * 2) * 1024;
    const int lc1 = lc0 + 1024;

#define STAGE_Q(gAp, gBp, Q, LAx, LBx) do { \
        gload16((gAp) + (size_t)r0 * 256 + (Q) * 64 + g16, lds + (LAx) + lc0); \
        gload16((gAp) + (size_t)r1 * 256 + (Q) * 64 + g16, lds + (LAx) + lc1); \
        gload16((gBp) + (size_t)r0 * 256 + (Q) * 64 + g16, lds + (LBx) + lc0); \
        gload16((gBp) + (size_t)r1 * 256 + (Q) * 64 + g16, lds + (LBx) + lc1); \
    } while (0)

#define GEMM_Q(LAx, LBx, ZERO) do { \
        half8 bf[4]; \
        _Pragma("unroll") \
        for (int j = 0; j < 4; ++j) \
            bf[j] = *reinterpret_cast<const half8*>(lds + (LBx) + (wcol + j * 16 + lr) * 64 + soff); \
        __builtin_amdgcn_s_setprio(1); \
        _Pragma("unroll") \
        for (int i = 0; i < 4; ++i) { \
            half8 af = *reinterpret_cast<const half8*>(lds + (LAx) + (wrow + i * 16 + lr) * 64 + soff); \
            _Pragma("unroll") \
            for (int j = 0; j < 4; ++j) \
                acc[i][j] = __builtin_amdgcn_mfma_f32_16x16x32_f16( \
                    af, bf[j], (ZERO) ? zero4 : acc[i][j], 0, 0, 0); \
        } \
        __builtin_amdgcn_s_setprio(0); \
    } while (0)

    const f32x4 zero4 = {0.f, 0.f, 0.f, 0.f};
    double acc_d = 0.0;

    // XCD-partitioned persistent tile range
    const int per_xcd = (ntiles + NXCD - 1) / NXCD;
    const int xcd = blockIdx.x & (NXCD - 1);
    const int bidx = blockIdx.x >> 3;
    const int stride = GRIDB / NXCD;   // 128
    int it = xcd * per_xcd + bidx;
    int tend = xcd * per_xcd + per_xcd;
    if (tend > ntiles) tend = ntiles;

    if (it < tend) {
        int bi, bj;
        decode_tile(it, T, bi, bj);
        const char* gA = (const char*)Z16 + (size_t)bi * (TILE * TD * 2);
        const char* gB = (const char*)Z16 + (size_t)bj * (TILE * TD * 2);

        // prologue: q0 -> buf0, q1 -> buf1, En both slices (wave 0, split)
        STAGE_Q(gA, gB, 0, LA0, LB0);
        STAGE_Q(gA, gB, 1, LA1, LB1);
        if (w == 0) {
            const float* eb = (l < 32) ? (En + (size_t)bi * TILE + (size_t)l * 4)
                                       : (En + (size_t)bj * TILE + (size_t)(l - 32) * 4);
            gload16(eb, lds + LEA);
        }

        while (true) {
            f32x4 acc[4][4];

            // ---- P0: quarter 0 (buf0); then stage q2 -> buf0
            if (w == 0) asm volatile("s_waitcnt vmcnt(5)" ::: "memory");
            else        asm volatile("s_waitcnt vmcnt(4)" ::: "memory");
            SCHEDB(); __builtin_amdgcn_s_barrier(); SCHEDB();
            GEMM_Q(LA0, LB0, true);
            asm volatile("s_waitcnt lgkmcnt(0)" ::: "memory");
            __builtin_amdgcn_s_barrier(); SCHEDB();
            STAGE_Q(gA, gB, 2, LA0, LB0);

            // ---- P1: quarter 1 (buf1); then stage q3 -> buf1
            if (w == 0) asm volatile("s_waitcnt vmcnt(5)" ::: "memory");
            else        asm volatile("s_waitcnt vmcnt(4)" ::: "memory");
            SCHEDB(); __builtin_amdgcn_s_barrier(); SCHEDB();
            GEMM_Q(LA1, LB1, false);
            asm volatile("s_waitcnt lgkmcnt(0)" ::: "memory");
            __builtin_amdgcn_s_barrier(); SCHEDB();
            STAGE_Q(gA, gB, 3, LA1, LB1);

            // ---- P2: quarter 2 (buf0); then stage q0 of NEXT tile -> buf0
            asm volatile("s_waitcnt vmcnt(4)" ::: "memory");
            SCHEDB(); __builtin_amdgcn_s_barrier(); SCHEDB();
            GEMM_Q(LA0, LB0, false);
            asm volatile("s_waitcnt lgkmcnt(0)" ::: "memory");
            __builtin_amdgcn_s_barrier(); SCHEDB();
            const int itn = it + stride;
            const bool more = (itn < tend);
            int bin = bi, bjn = bj;
            const char* gAn = gA;
            const char* gBn = gB;
            if (more) {
                decode_tile(itn, T, bin, bjn);
                gAn = (const char*)Z16 + (size_t)bin * (TILE * TD * 2);
                gBn = (const char*)Z16 + (size_t)bjn * (TILE * TD * 2);
                STAGE_Q(gAn, gBn, 0, LA0, LB0);
            }

            // ---- P3: quarter 3 (buf1); then stage q1 of next tile -> buf1
            if (more) asm volatile("s_waitcnt vmcnt(4)" ::: "memory");
            else      asm volatile("s_waitcnt vmcnt(0)" ::: "memory");
            SCHEDB(); __builtin_amdgcn_s_barrier(); SCHEDB();
            GEMM_Q(LA1, LB1, false);
            asm volatile("s_waitcnt lgkmcnt(0)" ::: "memory");
            __builtin_amdgcn_s_barrier(); SCHEDB();
            if (more) STAGE_Q(gAn, gBn, 1, LA1, LB1);

            // ---- epilogue: K = Ei * Ej * exp2(dot); En lazily from LDS
            // (En completion guaranteed: wave0's P2 vmcnt(4) covers the En
            //  load, and the P2 barrier orders it for all waves)
            float s = 0.f;
#pragma unroll
            for (int j = 0; j < 4; ++j) {
                float Ejv = *reinterpret_cast<const float*>(lds + LEB + (wcol + j * 16 + lr) * 4);
                float sj0 = 0.f, sj1 = 0.f;
#pragma unroll
                for (int i = 0; i < 4; ++i) {
                    f32x4 Eiv = *reinterpret_cast<const f32x4*>(lds + LEA + (wrow + i * 16 + kq * 4) * 4);
#pragma unroll
                    for (int r = 0; r < 4; ++r) {
                        float e = EXP2F(acc[i][j][r]);
                        if (r & 1) sj1 = fmaf(Eiv[r], e, sj1);
                        else       sj0 = fmaf(Eiv[r], e, sj0);
                    }
                }
                s = fmaf(Ejv, sj0 + sj1, s);
            }

            // ---- release En buffer, then issue En of next tile
            asm volatile("s_waitcnt lgkmcnt(0)" ::: "memory");
            SCHEDB(); __builtin_amdgcn_s_barrier(); SCHEDB();
            if (more && w == 0) {
                const float* eb = (l < 32) ? (En + (size_t)bin * TILE + (size_t)l * 4)
                                           : (En + (size_t)bjn * TILE + (size_t)(l - 32) * 4);
                gload16(eb, lds + LEA);
            }

            // ---- wave reduce -> running double accumulator
#pragma unroll
            for (int off = 32; off > 0; off >>= 1) s += __shfl_down(s, off, 64);
            {
                double wa = (bi * TILE < n) ? (1.0 / (double)n) : (-1.0 / (double)m);
                double wb = (bj * TILE < n) ? (1.0 / (double)n) : (-1.0 / (double)m);
                double wgt = wa * wb * ((bi == bj) ? 1.0 : 2.0);
                acc_d += wgt * (double)s;   // lane 0 holds the wave sum
            }

            if (!more) break;
            it = itn; bi = bin; bj = bjn; gA = gAn; gB = gBn;
        }
    }

    if (l == 0) partials[(size_t)blockIdx.x * 4 + w] = acc_d;
}

// ---------------------------------------------------------------------------
// Fallback fp32 path (round-1, proven): used only if ws/shape unsuitable
// ---------------------------------------------------------------------------
__global__ __launch_bounds__(256) void norms_kernel(const float* __restrict__ X,
                                                    const float* __restrict__ Y,
                                                    int n, int tot,
                                                    float* __restrict__ norms) {
    int r = blockIdx.x * 256 + threadIdx.x;
    if (r >= tot) return;
    const float* row = (r < n) ? (X + (size_t)r * TD) : (Y + (size_t)(r - n) * TD);
    float s = 0.f;
#pragma unroll
    for (int k = 0; k < TD; k += 4) {
        float4 v = *reinterpret_cast<const float4*>(row + k);
        s = fmaf(v.x, v.x, s); s = fmaf(v.y, v.y, s);
        s = fmaf(v.z, v.z, s); s = fmaf(v.w, v.w, s);
    }
    norms[r] = s;
}

__global__ __launch_bounds__(256, 2) void mmd_tile_kernel(const float* __restrict__ X,
                                                          const float* __restrict__ Y,
                                                          const float* __restrict__ norms,
                                                          double* __restrict__ partials,
                                                          int n, int m, int T) {
    __shared__ float sA[TD][BT];
    __shared__ float sB[TD][BT];
    __shared__ float sredf[4];

    const int t = blockIdx.x;
    int bi, bj;
    decode_tile(t, T, bi, bj);

    const int tid = threadIdx.x;
    {
        const int row = tid & 63;
        const int qb  = tid >> 6;
        const int ra = bi * BT + row;
        const int rb = bj * BT + row;
        const float* Arow = (ra < n) ? (X + (size_t)ra * TD) : (Y + (size_t)(ra - n) * TD);
        const float* Brow = (rb < n) ? (X + (size_t)rb * TD) : (Y + (size_t)(rb - n) * TD);
#pragma unroll
        for (int i = 0; i < 8; ++i) {
            const int q = qb + 4 * i;
            float4 va = *reinterpret_cast<const float4*>(Arow + 4 * q);
            sA[4 * q + 0][row] = va.x; sA[4 * q + 1][row] = va.y;
            sA[4 * q + 2][row] = va.z; sA[4 * q + 3][row] = va.w;
            float4 vb = *reinterpret_cast<const float4*>(Brow + 4 * q);
            sB[4 * q + 0][row] = vb.x; sB[4 * q + 1][row] = vb.y;
            sB[4 * q + 2][row] = vb.z; sB[4 * q + 3][row] = vb.w;
        }
    }
    __syncthreads();

    const int tx = tid & 15;
    const int ty = tid >> 4;
    float acc[4][4];
#pragma unroll
    for (int i = 0; i < 4; ++i)
#pragma unroll
        for (int j = 0; j < 4; ++j) acc[i][j] = 0.f;

#pragma unroll 16
    for (int k = 0; k < TD; ++k) {
        float4 a = *reinterpret_cast<const float4*>(&sA[k][ty * 4]);
        float4 b = *reinterpret_cast<const float4*>(&sB[k][tx * 4]);
        const float av[4] = {a.x, a.y, a.z, a.w};
        const float bv[4] = {b.x, b.y, b.z, b.w};
#pragma unroll
        for (int i = 0; i < 4; ++i)
#pragma unroll
            for (int j = 0; j < 4; ++j)
                acc[i][j] = fmaf(av[i], bv[j], acc[i][j]);
    }

    float nA[4], nB[4];
#pragma unroll
    for (int i = 0; i < 4; ++i) nA[i] = norms[bi * BT + ty * 4 + i];
#pragma unroll
    for (int j = 0; j < 4; ++j) nB[j] = norms[bj * BT + tx * 4 + j];

    const float cexp = -0.005f;
    float s = 0.f;
#pragma unroll
    for (int i = 0; i < 4; ++i)
#pragma unroll
        for (int j = 0; j < 4; ++j) {
            float d2 = fmaxf(nA[i] + nB[j] - 2.f * acc[i][j], 0.f);
            s += __expf(d2 * cexp);
        }

#pragma unroll
    for (int off = 32; off > 0; off >>= 1) s += __shfl_down(s, off, 64);
    if ((tid & 63) == 0) sredf[tid >> 6] = s;
    __syncthreads();
    if (tid == 0) {
        double wa = (bi * BT < n) ? (1.0 / (double)n) : (-1.0 / (double)m);
        double wb = (bj * BT < n) ? (1.0 / (double)n) : (-1.0 / (double)m);
        double wgt = wa * wb * ((bi == bj) ? 1.0 : 2.0);
        partials[t] = wgt * (double)(sredf[0] + sredf[1] + sredf[2] + sredf[3]);
    }
}

// ---------------------------------------------------------------------------
__global__ __launch_bounds__(256) void reduce_kernel(const double* __restrict__ partials,
                                                     int npart,
                                                     float* __restrict__ out) {
    __shared__ double sd[256];
    double s = 0.0;
    for (int i = threadIdx.x; i < npart; i += 256) s += partials[i];
    sd[threadIdx.x] = s;
    __syncthreads();
    for (int off = 128; off > 0; off >>= 1) {
        if ((int)threadIdx.x < off) sd[threadIdx.x] += sd[threadIdx.x + off];
        __syncthreads();
    }
    if (threadIdx.x == 0) out[0] = (float)sd[0];
}

// ---------------------------------------------------------------------------
extern "C" void kernel_launch(void* const* d_in, const int* in_sizes, int n_in,
                              void* d_out, int out_size, void* d_ws, size_t ws_size,
                              hipStream_t stream) {
    const float* X = (const float*)d_in[0];
    const float* Y = (const float*)d_in[1];
    float* out = (float*)d_out;

    const int n = in_sizes[0] / TD;
    const int m = in_sizes[1] / TD;
    const int tot = n + m;

    // fp16-MFMA path workspace: Z16 + En + per-(block,wave) partials
    const size_t z16_bytes = (size_t)tot * TD * 2;
    const size_t en_off    = (z16_bytes + 255) & ~(size_t)255;
    const size_t en_bytes  = (size_t)tot * 4;
    const size_t part_off  = ((en_off + en_bytes) + 255) & ~(size_t)255;
    const int Tm = tot / TILE;
    const int npart_m = Tm * (Tm + 1) / 2;
    const int nred = GRIDB * 4;
    const size_t needed = part_off + (size_t)nred * 8;

    if (ws_size >= needed && (tot % TILE) == 0 && (n % TILE) == 0) {
        _Float16* Z16 = (_Float16*)d_ws;
        float* En = (float*)((char*)d_ws + en_off);
        double* partials = (double*)((char*)d_ws + part_off);
        cvt_norms_kernel<<<(tot + 3) / 4, 256, 0, stream>>>(X, Y, n, tot, Z16, En);
        mmd_pipe_kernel<<<GRIDB, 256, 0, stream>>>(Z16, En, partials, n, m, Tm, npart_m);
        reduce_kernel<<<1, 256, 0, stream>>>(partials, nred, out);
    } else {
        const int T = tot / BT;
        const int npart = T * (T + 1) / 2;
        float* norms = (float*)d_ws;
        double* partials = (double*)((char*)d_ws + (((size_t)tot * 4 + 255) & ~(size_t)255));
        norms_kernel<<<(tot + 255) / 256, 256, 0, stream>>>(X, Y, n, tot, norms);
        mmd_tile_kernel<<<npart, 256, 0, stream>>>(X, Y, norms, partials, n, m, T);
        reduce_kernel<<<1, 256, 0, stream>>>(partials, npart, out);
    }
}